// Round 1
// baseline (373.097 us; speedup 1.0000x reference)
//
#include <hip/hip_runtime.h>
#include <stdint.h>
#include <stddef.h>

#define BB 4
#define TT 2048
#define DD 1024
#define HH 16
#define HDIM 64
#define BT (BB*TT)      // 8192 tokens
#define N1 (3*DD)       // 3072

typedef __attribute__((ext_vector_type(8))) short short8;
typedef __attribute__((ext_vector_type(4))) float floatx4;
typedef __attribute__((ext_vector_type(4))) float hipfloat4;
typedef __attribute__((ext_vector_type(4))) unsigned short ushortx4;

// fp32 -> bf16, round-to-nearest-even
__device__ __forceinline__ unsigned short f2b(float f) {
    unsigned int u = __float_as_uint(f);
    u += 0x7fffu + ((u >> 16) & 1u);
    return (unsigned short)(u >> 16);
}

// async global->LDS, 16B per lane; LDS dest is wave-uniform base + lane*16
__device__ __forceinline__ void gld_lds16(const void* g, void* l) {
    __builtin_amdgcn_global_load_lds(
        (__attribute__((address_space(1))) void*)(g),
        (__attribute__((address_space(3))) void*)(l), 16, 0, 0);
}

// ---------------------------------------------------------------------------
// fp32 -> bf16 elementwise (x)
// ---------------------------------------------------------------------------
__global__ void cvt_bf16(const float* __restrict__ src, unsigned short* __restrict__ dst, int n4) {
    int i = blockIdx.x * blockDim.x + threadIdx.x;
    if (i < n4) {
        floatx4 f = ((const floatx4*)src)[i];
        ushortx4 o;
        o.x = f2b(f.x); o.y = f2b(f.y); o.z = f2b(f.z); o.w = f2b(f.w);
        ((ushortx4*)dst)[i] = o;
    }
}

// ---------------------------------------------------------------------------
// fp32 [R][C] -> bf16 [C][R]  (weights to B^T layout)
// grid (C/32, R/32), block (32,8)
// ---------------------------------------------------------------------------
__global__ void transpose_cvt(const float* __restrict__ src, unsigned short* __restrict__ dst,
                              int R, int C) {
    __shared__ float tile[32][33];
    const int c0 = blockIdx.x * 32, r0 = blockIdx.y * 32;
    const int x = threadIdx.x, y = threadIdx.y;
    for (int yy = y; yy < 32; yy += 8)
        tile[yy][x] = src[(size_t)(r0 + yy) * C + c0 + x];
    __syncthreads();
    for (int yy = y; yy < 32; yy += 8)
        dst[(size_t)(c0 + yy) * R + r0 + x] = f2b(tile[x][yy]);
}

// ---------------------------------------------------------------------------
// V region of qkv [token][3072] -> vt [bh*64 + d][T]  (bf16)
// grid (64, T/32, 2), block (32,8)
// ---------------------------------------------------------------------------
__global__ void transpose_v(const unsigned short* __restrict__ qkv, unsigned short* __restrict__ vt) {
    __shared__ unsigned short tile[32][33];
    const int bh = blockIdx.x;
    const int b = bh >> 4, h = bh & 15;
    const int t0 = blockIdx.y * 32, d0 = blockIdx.z * 32;
    const int x = threadIdx.x, y = threadIdx.y;
    for (int yy = y; yy < 32; yy += 8)
        tile[yy][x] = qkv[(size_t)(b * TT + t0 + yy) * N1 + 2 * DD + h * HDIM + d0 + x];
    __syncthreads();
    for (int yy = y; yy < 32; yy += 8)
        vt[(size_t)(bh * HDIM + d0 + yy) * TT + t0 + x] = tile[x][yy];
}

// ---------------------------------------------------------------------------
// m97-style GEMM: C[M,N] = A[M,K] * Bt[N,K]^T ; bf16 in, fp32 acc
// 128x128 tile, BK=32, 256 threads (4 waves, each 64x64)
// OUT_BF16: 1 -> bf16 C, 0 -> fp32 C
// ---------------------------------------------------------------------------
template<int OUT_BF16>
__global__ __launch_bounds__(256, 2)
void gemm_bt(const unsigned short* __restrict__ A,
             const unsigned short* __restrict__ Bt,
             void* __restrict__ Cout, int M, int N, int K) {
    __shared__ unsigned short a_tile[128 * 32];
    __shared__ unsigned short b_tile[128 * 32];
    const int tid  = threadIdx.x;
    const int wave = tid >> 6;
    const int lane = tid & 63;
    const int quad = lane >> 4;
    const int lc   = lane & 15;
    const int wm = wave >> 1, wn = wave & 1;
    const int row0 = blockIdx.y * 128;
    const int col0 = blockIdx.x * 128;

    // staging: 8 chunks of 16 rows x 32 cols per operand; wave handles c and c+4
    const int c0 = wave, c1 = wave + 4;
    const int r_in = lane >> 2;        // 0..15 row within chunk
    const int kseg = (lane & 3) * 8;   // 0,8,16,24
    const unsigned short* gA0 = A  + (size_t)(row0 + c0 * 16 + r_in) * K + kseg;
    const unsigned short* gA1 = A  + (size_t)(row0 + c1 * 16 + r_in) * K + kseg;
    const unsigned short* gB0 = Bt + (size_t)(col0 + c0 * 16 + r_in) * K + kseg;
    const unsigned short* gB1 = Bt + (size_t)(col0 + c1 * 16 + r_in) * K + kseg;
    unsigned short* lA0 = &a_tile[c0 * 512];
    unsigned short* lA1 = &a_tile[c1 * 512];
    unsigned short* lB0 = &b_tile[c0 * 512];
    unsigned short* lB1 = &b_tile[c1 * 512];

    floatx4 acc[4][4];
    #pragma unroll
    for (int i = 0; i < 4; i++)
        #pragma unroll
        for (int j = 0; j < 4; j++)
            acc[i][j] = (floatx4){0.f, 0.f, 0.f, 0.f};

    const int nkt = K >> 5;
    for (int kt = 0; kt < nkt; ++kt) {
        __syncthreads();
        gld_lds16(gA0, lA0);
        gld_lds16(gA1, lA1);
        gld_lds16(gB0, lB0);
        gld_lds16(gB1, lB1);
        gA0 += 32; gA1 += 32; gB0 += 32; gB1 += 32;
        __syncthreads();

        short8 af[4], bf[4];
        #pragma unroll
        for (int mi = 0; mi < 4; ++mi)
            af[mi] = *(const short8*)&a_tile[(wm * 64 + mi * 16 + lc) * 32 + quad * 8];
        #pragma unroll
        for (int ni = 0; ni < 4; ++ni)
            bf[ni] = *(const short8*)&b_tile[(wn * 64 + ni * 16 + lc) * 32 + quad * 8];
        #pragma unroll
        for (int mi = 0; mi < 4; ++mi)
            #pragma unroll
            for (int ni = 0; ni < 4; ++ni)
                acc[mi][ni] = __builtin_amdgcn_mfma_f32_16x16x32_bf16(af[mi], bf[ni], acc[mi][ni], 0, 0, 0);
    }

    // epilogue: C/D layout row = quad*4 + r, col = lc  (m89/m91 verified)
    #pragma unroll
    for (int mi = 0; mi < 4; ++mi) {
        const int rbase = row0 + wm * 64 + mi * 16 + quad * 4;
        #pragma unroll
        for (int ni = 0; ni < 4; ++ni) {
            const int col = col0 + wn * 64 + ni * 16 + lc;
            #pragma unroll
            for (int r = 0; r < 4; ++r) {
                if (OUT_BF16)
                    ((unsigned short*)Cout)[(size_t)(rbase + r) * N + col] = f2b(acc[mi][ni][r]);
                else
                    ((float*)Cout)[(size_t)(rbase + r) * N + col] = acc[mi][ni][r];
            }
        }
    }
}

// ---------------------------------------------------------------------------
// Flash attention, causal. BM=128 q rows/block, BN=64 kv/tile, HD=64.
// grid (B*H, T/128), block 256 (4 waves; wave w -> q rows w*32..w*32+31)
// qkv: [token][3072] bf16 ; vt: [bh*64+d][T] bf16 ; out: [token][1024] bf16
// ---------------------------------------------------------------------------
__global__ __launch_bounds__(256, 2)
void attn_fwd(const unsigned short* __restrict__ qkv,
              const unsigned short* __restrict__ vt,
              unsigned short* __restrict__ out) {
    __shared__ unsigned short q_tile[128 * 72];   // padded stride 72 (144B, 16B-aligned)
    __shared__ unsigned short k_tile[64 * 72];
    __shared__ unsigned short v_tile[64 * 72];    // vt layout: row=d, col=kv
    __shared__ unsigned short p_tile[128 * 72];
    const int bh = blockIdx.x;
    const int b = bh >> 4, h = bh & 15;
    const int qt = blockIdx.y;
    const int q0 = qt * 128;
    const int tid = threadIdx.x;
    const int wave = tid >> 6, lane = tid & 63;
    const int quad = lane >> 4, lc = lane & 15;

    // Q tile: 128 rows x 64 cols, 8x 16B segs per row
    for (int s = tid; s < 1024; s += 256) {
        int r = s >> 3, seg = s & 7;
        short8 v = *(const short8*)(qkv + (size_t)(b * TT + q0 + r) * N1 + h * HDIM + seg * 8);
        *(short8*)&q_tile[r * 72 + seg * 8] = v;
    }
    __syncthreads();

    // Q A-fragments in registers for whole kernel
    short8 qf[2][2];
    #pragma unroll
    for (int mi = 0; mi < 2; ++mi)
        #pragma unroll
        for (int kk = 0; kk < 2; ++kk)
            qf[mi][kk] = *(const short8*)&q_tile[(wave * 32 + mi * 16 + lc) * 72 + kk * 32 + quad * 8];

    float m_st[2][4], l_st[2][4];
    floatx4 o_acc[2][4];
    #pragma unroll
    for (int mi = 0; mi < 2; ++mi) {
        #pragma unroll
        for (int r = 0; r < 4; ++r) { m_st[mi][r] = -1e30f; l_st[mi][r] = 0.f; }
        #pragma unroll
        for (int ni = 0; ni < 4; ++ni) o_acc[mi][ni] = (floatx4){0.f, 0.f, 0.f, 0.f};
    }

    const int ntiles = 2 * qt + 2;   // causal: kv up to q0+127
    for (int kvt = 0; kvt < ntiles; ++kvt) {
        const int kv0 = kvt * 64;
        __syncthreads();   // protect k_tile/v_tile from previous iter's readers
        for (int s = tid; s < 512; s += 256) {
            int r = s >> 3, seg = s & 7;
            short8 v = *(const short8*)(qkv + (size_t)(b * TT + kv0 + r) * N1 + DD + h * HDIM + seg * 8);
            *(short8*)&k_tile[r * 72 + seg * 8] = v;
        }
        for (int s = tid; s < 512; s += 256) {
            int d = s >> 3, seg = s & 7;
            short8 v = *(const short8*)(vt + (size_t)(bh * HDIM + d) * TT + kv0 + seg * 8);
            *(short8*)&v_tile[d * 72 + seg * 8] = v;
        }
        __syncthreads();

        // S = Q K^T   [32 rows per wave x 64 kv]
        short8 kf[4][2];
        #pragma unroll
        for (int ni = 0; ni < 4; ++ni)
            #pragma unroll
            for (int kk = 0; kk < 2; ++kk)
                kf[ni][kk] = *(const short8*)&k_tile[(ni * 16 + lc) * 72 + kk * 32 + quad * 8];
        floatx4 s_acc[2][4];
        #pragma unroll
        for (int mi = 0; mi < 2; ++mi)
            #pragma unroll
            for (int ni = 0; ni < 4; ++ni)
                s_acc[mi][ni] = (floatx4){0.f, 0.f, 0.f, 0.f};
        #pragma unroll
        for (int kk = 0; kk < 2; ++kk)
            #pragma unroll
            for (int mi = 0; mi < 2; ++mi)
                #pragma unroll
                for (int ni = 0; ni < 4; ++ni)
                    s_acc[mi][ni] = __builtin_amdgcn_mfma_f32_16x16x32_bf16(qf[mi][kk], kf[ni][kk], s_acc[mi][ni], 0, 0, 0);

        // scale + causal mask + online softmax (per row: quad-wide shfl reduce)
        #pragma unroll
        for (int mi = 0; mi < 2; ++mi) {
            #pragma unroll
            for (int r = 0; r < 4; ++r) {
                const int rg = q0 + wave * 32 + mi * 16 + quad * 4 + r;
                float mx = -1e30f;
                #pragma unroll
                for (int ni = 0; ni < 4; ++ni) {
                    float sv = s_acc[mi][ni][r] * 0.125f;
                    sv = ((kv0 + ni * 16 + lc) <= rg) ? sv : -1e30f;
                    s_acc[mi][ni][r] = sv;
                    mx = fmaxf(mx, sv);
                }
                mx = fmaxf(mx, __shfl_xor(mx, 1));
                mx = fmaxf(mx, __shfl_xor(mx, 2));
                mx = fmaxf(mx, __shfl_xor(mx, 4));
                mx = fmaxf(mx, __shfl_xor(mx, 8));
                const float mnew  = fmaxf(m_st[mi][r], mx);
                const float alpha = __expf(m_st[mi][r] - mnew);
                m_st[mi][r] = mnew;
                float rs = 0.f;
                #pragma unroll
                for (int ni = 0; ni < 4; ++ni) {
                    float p = __expf(s_acc[mi][ni][r] - mnew);
                    rs += p;
                    p_tile[(wave * 32 + mi * 16 + quad * 4 + r) * 72 + ni * 16 + lc] = f2b(p);
                }
                rs += __shfl_xor(rs, 1);
                rs += __shfl_xor(rs, 2);
                rs += __shfl_xor(rs, 4);
                rs += __shfl_xor(rs, 8);
                l_st[mi][r] = l_st[mi][r] * alpha + rs;
                #pragma unroll
                for (int ni = 0; ni < 4; ++ni) o_acc[mi][ni][r] *= alpha;
            }
        }

        // O += P V  (P rows are per-wave -> no barrier needed; same-wave LDS is ordered)
        short8 vf[4][2];
        #pragma unroll
        for (int ni = 0; ni < 4; ++ni)
            #pragma unroll
            for (int kk = 0; kk < 2; ++kk)
                vf[ni][kk] = *(const short8*)&v_tile[(ni * 16 + lc) * 72 + kk * 32 + quad * 8];
        #pragma unroll
        for (int mi = 0; mi < 2; ++mi)
            #pragma unroll
            for (int kk = 0; kk < 2; ++kk) {
                short8 pf = *(const short8*)&p_tile[(wave * 32 + mi * 16 + lc) * 72 + kk * 32 + quad * 8];
                #pragma unroll
                for (int ni = 0; ni < 4; ++ni)
                    o_acc[mi][ni] = __builtin_amdgcn_mfma_f32_16x16x32_bf16(pf, vf[ni][kk], o_acc[mi][ni], 0, 0, 0);
            }
    }

    // epilogue: out = O / l
    #pragma unroll
    for (int mi = 0; mi < 2; ++mi) {
        #pragma unroll
        for (int r = 0; r < 4; ++r) {
            const int rg = q0 + wave * 32 + mi * 16 + quad * 4 + r;
            const float inv = 1.0f / l_st[mi][r];
            #pragma unroll
            for (int ni = 0; ni < 4; ++ni)
                out[(size_t)(b * TT + rg) * DD + h * HDIM + ni * 16 + lc] = f2b(o_acc[mi][ni][r] * inv);
        }
    }
}

// ---------------------------------------------------------------------------
extern "C" void kernel_launch(void* const* d_in, const int* in_sizes, int n_in,
                              void* d_out, int out_size, void* d_ws, size_t ws_size,
                              hipStream_t stream) {
    const float* x     = (const float*)d_in[0];   // [B,T,D]
    const float* w_qkv = (const float*)d_in[1];   // [D, 3D]
    const float* w_out = (const float*)d_in[2];   // [D, D]
    float* out = (float*)d_out;                   // [B,T,D] fp32

    unsigned short* ws  = (unsigned short*)d_ws;
    unsigned short* xb  = ws;                                  // 8192*1024   (also reused for attn out)
    unsigned short* qkv = xb  + (size_t)BT * DD;               // 8192*3072
    unsigned short* wqT = qkv + (size_t)BT * N1;               // 3072*1024
    unsigned short* woT = wqT + (size_t)N1 * DD;               // 1024*1024
    unsigned short* vtb = woT + (size_t)DD * DD;               // 4096*2048

    // 1. x -> bf16
    cvt_bf16<<<(BT * DD / 4 + 255) / 256, 256, 0, stream>>>(x, xb, BT * DD / 4);
    // 2. weights -> B^T bf16
    transpose_cvt<<<dim3(N1 / 32, DD / 32), dim3(32, 8), 0, stream>>>(w_qkv, wqT, DD, N1);
    transpose_cvt<<<dim3(DD / 32, DD / 32), dim3(32, 8), 0, stream>>>(w_out, woT, DD, DD);
    // 3. QKV = x @ w_qkv   (bf16 out)
    gemm_bt<1><<<dim3(N1 / 128, BT / 128), 256, 0, stream>>>(xb, wqT, qkv, BT, N1, DD);
    // 4. V -> [bh, d, T]
    transpose_v<<<dim3(BB * HH, TT / 32, 2), dim3(32, 8), 0, stream>>>(qkv, vtb);
    // 5. flash attention (writes over xb)
    attn_fwd<<<dim3(BB * HH, TT / 128), 256, 0, stream>>>(qkv, vtb, xb);
    // 6. out = attn @ w_out  (fp32 out)
    gemm_bt<0><<<dim3(DD / 128, BT / 128), 256, 0, stream>>>(xb, woT, out, BT, DD, DD);
}